// Round 2
// baseline (405.758 us; speedup 1.0000x reference)
//
#include <hip/hip_runtime.h>
#include <hip/hip_bf16.h>

#define M_TOK 8192
#define IN_F  1024
#define OUT_F 1024
#define N_EXP 8

typedef __attribute__((ext_vector_type(8))) _Float16 f16x8;
typedef __attribute__((ext_vector_type(4))) _Float16 f16x4;
typedef __attribute__((ext_vector_type(4))) float    f32x4;

// ---------------- prep: gate softmax + x fp32 -> f16 (fused, both read x) ----------------
__global__ void moe_prep_kernel(const float* __restrict__ x, const float* __restrict__ Wg,
                                const float* __restrict__ bg, float* __restrict__ g,
                                _Float16* __restrict__ xh) {
    int token = blockIdx.x * 4 + (threadIdx.x >> 6);
    int lane  = threadIdx.x & 63;
    const float* xr = x + (size_t)token * IN_F;
    _Float16* xhr = xh + (size_t)token * IN_F;
    float acc[8] = {0.f,0.f,0.f,0.f,0.f,0.f,0.f,0.f};
#pragma unroll
    for (int k = 0; k < IN_F / 64; ++k) {
        int i = lane + k * 64;
        float xv = xr[i];
        xhr[i] = (_Float16)xv;
        const float* wr = Wg + i * 8;
#pragma unroll
        for (int e = 0; e < 8; ++e) acc[e] = fmaf(xv, wr[e], acc[e]);
    }
#pragma unroll
    for (int e = 0; e < 8; ++e) {
        float v = acc[e];
#pragma unroll
        for (int off = 32; off > 0; off >>= 1) v += __shfl_xor(v, off, 64);
        acc[e] = v + bg[e];
    }
    float mx = acc[0];
#pragma unroll
    for (int e = 1; e < 8; ++e) mx = fmaxf(mx, acc[e]);
    float sum = 0.f;
#pragma unroll
    for (int e = 0; e < 8; ++e) { acc[e] = __expf(acc[e] - mx); sum += acc[e]; }
    float inv = 1.0f / sum;
    if (lane == 0) {
        float4 p0 = {acc[0]*inv, acc[1]*inv, acc[2]*inv, acc[3]*inv};
        float4 p1 = {acc[4]*inv, acc[5]*inv, acc[6]*inv, acc[7]*inv};
        float4* gp = (float4*)(g + (size_t)token * 8);
        gp[0] = p0; gp[1] = p1;
    }
}

// ---------------- We [e][i][o] fp32 -> wt [e][o][i] f16 (B^T per expert) ----------------
__global__ void moe_transpose_we_kernel(const float* __restrict__ We, _Float16* __restrict__ wt) {
    __shared__ float t[64][65];
    int e  = blockIdx.z;
    int i0 = blockIdx.x * 64;   // in_f tile
    int o0 = blockIdx.y * 64;   // out_f tile
    const float* src = We + ((size_t)e << 20);
    int oo = threadIdx.x & 63;
    int ib = threadIdx.x >> 6;  // 0..3
#pragma unroll
    for (int r = 0; r < 16; ++r) {
        int i = ib + r * 4;
        t[i][oo] = src[(size_t)(i0 + i) * OUT_F + o0 + oo];
    }
    __syncthreads();
    _Float16* dst = wt + ((size_t)e << 20);
#pragma unroll
    for (int r = 0; r < 16; ++r) {
        int o = ib + r * 4;
        dst[(size_t)(o0 + o) * IN_F + i0 + oo] = (_Float16)t[oo][o];
    }
}

// ---------------- fused-expert MFMA GEMM: out = sum_e g[:,e]*(xh@We[e] + be[e]) ----------------
__device__ __forceinline__ void async16(const void* gp, void* lp) {
    __builtin_amdgcn_global_load_lds((const __attribute__((address_space(1))) void*)gp,
                                     (__attribute__((address_space(3))) void*)lp, 16, 0, 0);
}

__global__ __launch_bounds__(256, 2) void moe_gemm_kernel(
    const _Float16* __restrict__ xh,   // [M][K] f16
    const _Float16* __restrict__ wt,   // [E][N][K] f16  (B^T per expert)
    const float* __restrict__ g,       // [M][E]
    const float* __restrict__ be,      // [E][N]
    float* __restrict__ out)           // [M][N] fp32, plain stores
{
    __shared__ __align__(16) _Float16 As[128 * 64];
    __shared__ __align__(16) _Float16 Bs[128 * 64];
    __shared__ float gs[128 * 8];      // gate block, row-major [row][e]
    __shared__ float bs[8 * 128];      // bias slice [e][col]

    const int tid  = threadIdx.x;
    const int lane = tid & 63;
    const int wave = tid >> 6;
    const size_t m0 = (size_t)blockIdx.y * 128;
    const size_t n0 = (size_t)blockIdx.x * 128;

    // g[m0..m0+128) x 8 experts is 1024 contiguous floats
    ((float4*)gs)[tid] = ((const float4*)(g + m0 * 8))[tid];
#pragma unroll
    for (int r = 0; r < 4; ++r) {
        int idx = r * 256 + tid;
        int eb = idx >> 7, col = idx & 127;
        bs[idx] = be[eb * 1024 + n0 + col];
    }
    __syncthreads();

    // Staging: linear 16B chunk L = j*256 + tid -> LDS row = L>>3, phys c8 = L&7.
    // XOR swizzle baked into the GLOBAL source: logical k-chunk = phys_c8 ^ (row&7).
    const int rb = tid >> 3;                  // row within 32-row group
    const int c8 = (tid & 7) ^ (rb & 7);      // swizzled logical k-chunk
    const _Float16* pA = xh + (m0 + rb) * (size_t)IN_F + c8 * 8;
    const _Float16* pB0 = wt + (n0 + rb) * (size_t)IN_F + c8 * 8;
    char* lA = (char*)As + tid * 16;
    char* lB = (char*)Bs + tid * 16;

    // Fragment read addresses (bytes). A[m=lane&15][k=quad*8+j]; phys c8 = c8_logical ^ (row&7)
    const int quad = lane >> 4;
    const int ml   = lane & 15;
    const int wm   = (wave >> 1) * 64;
    const int wn   = (wave & 1) * 64;
    const int raA0 = (wm + ml) * 128 + (((0 * 4 + quad) ^ (lane & 7)) * 16);
    const int raA1 = (wm + ml) * 128 + (((1 * 4 + quad) ^ (lane & 7)) * 16);
    const int raB0 = (wn + ml) * 128 + (((0 * 4 + quad) ^ (lane & 7)) * 16);
    const int raB1 = (wn + ml) * 128 + (((1 * 4 + quad) ^ (lane & 7)) * 16);

    f32x4 fin[4][4] = {};

    for (int e = 0; e < 8; ++e) {
        const _Float16* pB = pB0 + ((size_t)e << 20);
        // acc starts at the bias (same cost as zero-init; folds be for free)
        f32x4 acc[4][4];
#pragma unroll
        for (int jn = 0; jn < 4; ++jn) {
            float b = bs[e * 128 + wn + jn * 16 + ml];
            f32x4 bv = {b, b, b, b};
#pragma unroll
            for (int i = 0; i < 4; ++i) acc[i][jn] = bv;
        }

        for (int kt = 0; kt < IN_F / 64; ++kt) {
            const _Float16* sA = pA + kt * 64;
            const _Float16* sB = pB + kt * 64;
#pragma unroll
            for (int j = 0; j < 4; ++j) {
                async16(sA + j * 32 * IN_F, lA + j * 4096);
                async16(sB + j * 32 * IN_F, lB + j * 4096);
            }
            __syncthreads();
#pragma unroll
            for (int s = 0; s < 2; ++s) {
                const int rA = s ? raA1 : raA0;
                const int rB = s ? raB1 : raB0;
                f16x8 af[4], bf[4];
#pragma unroll
                for (int t = 0; t < 4; ++t) af[t] = *(const f16x8*)((const char*)As + rA + t * 2048);
#pragma unroll
                for (int t = 0; t < 4; ++t) bf[t] = *(const f16x8*)((const char*)Bs + rB + t * 2048);
#pragma unroll
                for (int i = 0; i < 4; ++i)
#pragma unroll
                    for (int jn = 0; jn < 4; ++jn)
                        acc[i][jn] = __builtin_amdgcn_mfma_f32_16x16x32_f16(af[i], bf[jn], acc[i][jn], 0, 0, 0);
            }
            __syncthreads();
        }

        // fold: fin += g[row,e] * acc   (gate values to registers first: 16 LDS reads)
        float gr[4][4];
#pragma unroll
        for (int i = 0; i < 4; ++i)
#pragma unroll
            for (int r = 0; r < 4; ++r) gr[i][r] = gs[(wm + i * 16 + quad * 4 + r) * 8 + e];
#pragma unroll
        for (int i = 0; i < 4; ++i)
#pragma unroll
            for (int jn = 0; jn < 4; ++jn)
#pragma unroll
                for (int r = 0; r < 4; ++r)
                    fin[i][jn][r] = fmaf(gr[i][r], acc[i][jn][r], fin[i][jn][r]);
    }

    // Epilogue: plain stores. C/D layout col = lane&15, row = quad*4 + reg.
#pragma unroll
    for (int i = 0; i < 4; ++i) {
        const int rowb = wm + i * 16 + quad * 4;
#pragma unroll
        for (int jn = 0; jn < 4; ++jn) {
            const size_t col = n0 + wn + jn * 16 + ml;
#pragma unroll
            for (int r = 0; r < 4; ++r)
                out[(m0 + rowb + r) * (size_t)OUT_F + col] = fin[i][jn][r];
        }
    }
}

extern "C" void kernel_launch(void* const* d_in, const int* in_sizes, int n_in,
                              void* d_out, int out_size, void* d_ws, size_t ws_size,
                              hipStream_t stream) {
    const float* x  = (const float*)d_in[0];
    const float* We = (const float*)d_in[1];
    const float* be = (const float*)d_in[2];
    const float* Wg = (const float*)d_in[3];
    const float* bg = (const float*)d_in[4];
    float* out = (float*)d_out;

    char* ws = (char*)d_ws;
    float*    g  = (float*)ws;                                   // 8192*8*4    = 256 KB
    _Float16* xh = (_Float16*)(ws + (1 << 18));                  // 8192*1024*2 = 16 MB
    _Float16* wt = (_Float16*)(ws + (1 << 18) + (1 << 24));      // 8*1024*1024*2 = 16 MB

    moe_prep_kernel<<<M_TOK / 4, 256, 0, stream>>>(x, Wg, bg, g, xh);
    moe_transpose_we_kernel<<<dim3(IN_F / 64, OUT_F / 64, N_EXP), 256, 0, stream>>>(We, wt);
    moe_gemm_kernel<<<dim3(OUT_F / 128, M_TOK / 128), 256, 0, stream>>>(xh, wt, g, be, out);
}

// Round 3
// 352.530 us; speedup vs baseline: 1.1510x; 1.1510x over previous
//
#include <hip/hip_runtime.h>
#include <hip/hip_bf16.h>

#define M_TOK 8192
#define IN_F  1024
#define OUT_F 1024
#define N_EXP 8
#define KT    8192   // fused K dimension: 8 experts x 1024

typedef __attribute__((ext_vector_type(8))) _Float16 f16x8;
typedef __attribute__((ext_vector_type(4))) _Float16 f16x4;
typedef __attribute__((ext_vector_type(4))) float    f32x4;

// ---- prep: gate softmax + materialize A'[m][e*1024+k] = g[m,e]*x[m,k] (f16) ----
__global__ void moe_prep_kernel(const float* __restrict__ x, const float* __restrict__ Wg,
                                const float* __restrict__ bg, float* __restrict__ g,
                                _Float16* __restrict__ xs) {
    int token = blockIdx.x * 4 + (threadIdx.x >> 6);
    int lane  = threadIdx.x & 63;
    const float* xr = x + (size_t)token * IN_F;
    float4 xv[4];
    float acc[8] = {0.f,0.f,0.f,0.f,0.f,0.f,0.f,0.f};
#pragma unroll
    for (int kc = 0; kc < 4; ++kc) {
        int i = kc * 256 + lane * 4;
        xv[kc] = *(const float4*)(xr + i);
        float xj[4] = {xv[kc].x, xv[kc].y, xv[kc].z, xv[kc].w};
#pragma unroll
        for (int j = 0; j < 4; ++j) {
            const float4* wr = (const float4*)(Wg + (size_t)(i + j) * 8);
            float4 w0 = wr[0], w1 = wr[1];
            acc[0] = fmaf(xj[j], w0.x, acc[0]); acc[1] = fmaf(xj[j], w0.y, acc[1]);
            acc[2] = fmaf(xj[j], w0.z, acc[2]); acc[3] = fmaf(xj[j], w0.w, acc[3]);
            acc[4] = fmaf(xj[j], w1.x, acc[4]); acc[5] = fmaf(xj[j], w1.y, acc[5]);
            acc[6] = fmaf(xj[j], w1.z, acc[6]); acc[7] = fmaf(xj[j], w1.w, acc[7]);
        }
    }
#pragma unroll
    for (int e = 0; e < 8; ++e) {
        float v = acc[e];
#pragma unroll
        for (int off = 32; off > 0; off >>= 1) v += __shfl_xor(v, off, 64);
        acc[e] = v + bg[e];
    }
    float mx = acc[0];
#pragma unroll
    for (int e = 1; e < 8; ++e) mx = fmaxf(mx, acc[e]);
    float sum = 0.f;
#pragma unroll
    for (int e = 0; e < 8; ++e) { acc[e] = __expf(acc[e] - mx); sum += acc[e]; }
    float inv = 1.0f / sum;
#pragma unroll
    for (int e = 0; e < 8; ++e) acc[e] *= inv;
    if (lane == 0) {
        float4 p0 = {acc[0], acc[1], acc[2], acc[3]};
        float4 p1 = {acc[4], acc[5], acc[6], acc[7]};
        float4* gp = (float4*)(g + (size_t)token * 8);
        gp[0] = p0; gp[1] = p1;
    }
    _Float16* xsr = xs + (size_t)token * KT;
#pragma unroll
    for (int e = 0; e < 8; ++e) {
        float ge = acc[e];
#pragma unroll
        for (int kc = 0; kc < 4; ++kc) {
            f16x4 h = { (_Float16)(ge * xv[kc].x), (_Float16)(ge * xv[kc].y),
                        (_Float16)(ge * xv[kc].z), (_Float16)(ge * xv[kc].w) };
            *(f16x4*)(xsr + e * 1024 + kc * 256 + lane * 4) = h;
        }
    }
}

// ---- We [e][i][o] fp32 -> wt2 [o][e*1024+i] f16 (stacked B'^T) ----
__global__ void moe_transpose_we_kernel(const float* __restrict__ We, _Float16* __restrict__ wt) {
    __shared__ float t[64][65];
    int e  = blockIdx.z;
    int i0 = blockIdx.x * 64;   // in_f tile
    int o0 = blockIdx.y * 64;   // out_f tile
    const float* src = We + ((size_t)e << 20);
    int oo = threadIdx.x & 63;
    int ib = threadIdx.x >> 6;  // 0..3
#pragma unroll
    for (int r = 0; r < 16; ++r) {
        int i = ib + r * 4;
        t[i][oo] = src[(size_t)(i0 + i) * OUT_F + o0 + oo];
    }
    __syncthreads();
#pragma unroll
    for (int r = 0; r < 16; ++r) {
        int o = ib + r * 4;
        wt[(size_t)(o0 + o) * KT + (size_t)e * 1024 + i0 + oo] = (_Float16)t[oo][o];
    }
}

// ---- out init: out[n][o] = sum_e g[n][e] * be[e][o] ----
__global__ void moe_init_out_kernel(const float* __restrict__ g, const float* __restrict__ be,
                                    float* __restrict__ out) {
    int idx = blockIdx.x * 256 + threadIdx.x;      // M*OUT/4 threads
    int n   = idx >> 8;                            // OUT_F/4 = 256 float4 per row
    int o4  = idx & 255;
    const float4* be4 = (const float4*)be;
    const float* gr = g + (size_t)n * 8;
    float4 a = {0.f, 0.f, 0.f, 0.f};
#pragma unroll
    for (int e = 0; e < 8; ++e) {
        float ge = gr[e];
        float4 b = be4[e * 256 + o4];
        a.x = fmaf(ge, b.x, a.x); a.y = fmaf(ge, b.y, a.y);
        a.z = fmaf(ge, b.z, a.z); a.w = fmaf(ge, b.w, a.w);
    }
    ((float4*)out)[idx] = a;
}

// ---- single fused GEMM: out += A'(8192x8192) @ B'(8192x1024), split-K=2 ----
__device__ __forceinline__ void async16(const void* gp, void* lp) {
    __builtin_amdgcn_global_load_lds((const __attribute__((address_space(1))) void*)gp,
                                     (__attribute__((address_space(3))) void*)lp, 16, 0, 0);
}

__global__ __launch_bounds__(256, 4) void moe_gemm_kernel(
    const _Float16* __restrict__ xs,   // [M][KT] f16  (gate-scaled A')
    const _Float16* __restrict__ wt,   // [N][KT] f16  (B'^T)
    float* __restrict__ out)           // [M][N] fp32, atomic accumulate (pre-init w/ bias)
{
    __shared__ __align__(16) _Float16 As[128 * 64];
    __shared__ __align__(16) _Float16 Bs[128 * 64];

    const int tid  = threadIdx.x;
    const int lane = tid & 63;
    const int wave = tid >> 6;
    const size_t m0 = (size_t)blockIdx.y * 128;
    const size_t n0 = (size_t)blockIdx.x * 128;
    const size_t k0 = (size_t)blockIdx.z * (KT / 2);

    // Staging: linear 16B chunk L = j*256 + tid -> LDS row = L>>3, phys c8 = L&7.
    // XOR swizzle baked into the GLOBAL source: logical k-chunk = phys_c8 ^ (row&7).
    const int rb = tid >> 3;                  // row within 32-row group
    const int c8 = (tid & 7) ^ (rb & 7);      // swizzled logical k-chunk
    const _Float16* pA = xs + (m0 + rb) * (size_t)KT + k0 + c8 * 8;
    const _Float16* pB = wt + (n0 + rb) * (size_t)KT + k0 + c8 * 8;
    char* lA = (char*)As + tid * 16;
    char* lB = (char*)Bs + tid * 16;

    // Fragment read addresses (bytes). A[m=lane&15][k=quad*8+j]; phys c8 = c8_logical ^ (row&7)
    const int quad = lane >> 4;
    const int ml   = lane & 15;
    const int wm   = (wave >> 1) * 64;
    const int wn   = (wave & 1) * 64;
    const int raA0 = (wm + ml) * 128 + (((0 * 4 + quad) ^ (lane & 7)) * 16);
    const int raA1 = (wm + ml) * 128 + (((1 * 4 + quad) ^ (lane & 7)) * 16);
    const int raB0 = (wn + ml) * 128 + (((0 * 4 + quad) ^ (lane & 7)) * 16);
    const int raB1 = (wn + ml) * 128 + (((1 * 4 + quad) ^ (lane & 7)) * 16);

    f32x4 acc[4][4] = {};

    for (int kt = 0; kt < (KT / 2) / 64; ++kt) {
        const _Float16* sA = pA + kt * 64;
        const _Float16* sB = pB + kt * 64;
#pragma unroll
        for (int j = 0; j < 4; ++j) {
            async16(sA + j * 32 * (size_t)KT, lA + j * 4096);
            async16(sB + j * 32 * (size_t)KT, lB + j * 4096);
        }
        __syncthreads();
#pragma unroll
        for (int s = 0; s < 2; ++s) {
            const int rA = s ? raA1 : raA0;
            const int rB = s ? raB1 : raB0;
            f16x8 af[4], bf[4];
#pragma unroll
            for (int t = 0; t < 4; ++t) af[t] = *(const f16x8*)((const char*)As + rA + t * 2048);
#pragma unroll
            for (int t = 0; t < 4; ++t) bf[t] = *(const f16x8*)((const char*)Bs + rB + t * 2048);
#pragma unroll
            for (int i = 0; i < 4; ++i)
#pragma unroll
                for (int jn = 0; jn < 4; ++jn)
                    acc[i][jn] = __builtin_amdgcn_mfma_f32_16x16x32_f16(af[i], bf[jn], acc[i][jn], 0, 0, 0);
        }
        __syncthreads();
    }

    // Epilogue: C/D layout col = lane&15, row = quad*4 + reg. 2-way split-K atomic add.
#pragma unroll
    for (int i = 0; i < 4; ++i) {
        const int rowb = wm + i * 16 + quad * 4;
#pragma unroll
        for (int jn = 0; jn < 4; ++jn) {
            const size_t col = n0 + wn + jn * 16 + ml;
#pragma unroll
            for (int r = 0; r < 4; ++r)
                unsafeAtomicAdd(out + (m0 + rowb + r) * (size_t)OUT_F + col, acc[i][jn][r]);
        }
    }
}

extern "C" void kernel_launch(void* const* d_in, const int* in_sizes, int n_in,
                              void* d_out, int out_size, void* d_ws, size_t ws_size,
                              hipStream_t stream) {
    const float* x  = (const float*)d_in[0];
    const float* We = (const float*)d_in[1];
    const float* be = (const float*)d_in[2];
    const float* Wg = (const float*)d_in[3];
    const float* bg = (const float*)d_in[4];
    float* out = (float*)d_out;

    char* ws = (char*)d_ws;
    float*    g   = (float*)ws;                                  // 256 KB
    _Float16* xs  = (_Float16*)(ws + (1 << 18));                 // 8192*8192*2 = 128 MiB
    _Float16* wt2 = (_Float16*)(ws + (1 << 18) + ((size_t)1 << 27)); // 1024*8192*2 = 16 MiB
    // total ws needed: ~145 MB

    moe_prep_kernel<<<M_TOK / 4, 256, 0, stream>>>(x, Wg, bg, g, xs);
    moe_transpose_we_kernel<<<dim3(IN_F / 64, OUT_F / 64, N_EXP), 256, 0, stream>>>(We, wt2);
    moe_init_out_kernel<<<(M_TOK * OUT_F / 4) / 256, 256, 0, stream>>>(g, be, out);
    moe_gemm_kernel<<<dim3(OUT_F / 128, M_TOK / 128, 2), 256, 0, stream>>>(xs, wt2, out);
}

// Round 4
// 324.121 us; speedup vs baseline: 1.2519x; 1.0876x over previous
//
#include <hip/hip_runtime.h>
#include <hip/hip_bf16.h>

#define M_TOK 8192
#define IN_F  1024
#define OUT_F 1024
#define N_EXP 8
#define KT    8192   // fused K dimension: 8 experts x 1024

typedef __attribute__((ext_vector_type(8))) _Float16 f16x8;
typedef __attribute__((ext_vector_type(4))) _Float16 f16x4;
typedef __attribute__((ext_vector_type(4))) float    f32x4;

// ---- prep: gate softmax, x -> f16, and out init with gate-weighted bias ----
__global__ void moe_prep_kernel(const float* __restrict__ x, const float* __restrict__ Wg,
                                const float* __restrict__ bg, const float* __restrict__ be,
                                float* __restrict__ g, _Float16* __restrict__ xh,
                                float* __restrict__ out) {
    int token = blockIdx.x * 4 + (threadIdx.x >> 6);
    int lane  = threadIdx.x & 63;
    const float* xr = x + (size_t)token * IN_F;
    float4 xv[4];
    float acc[8] = {0.f,0.f,0.f,0.f,0.f,0.f,0.f,0.f};
#pragma unroll
    for (int kc = 0; kc < 4; ++kc) {
        int i = kc * 256 + lane * 4;
        xv[kc] = *(const float4*)(xr + i);
        float xj[4] = {xv[kc].x, xv[kc].y, xv[kc].z, xv[kc].w};
#pragma unroll
        for (int j = 0; j < 4; ++j) {
            const float4* wr = (const float4*)(Wg + (size_t)(i + j) * 8);
            float4 w0 = wr[0], w1 = wr[1];
            acc[0] = fmaf(xj[j], w0.x, acc[0]); acc[1] = fmaf(xj[j], w0.y, acc[1]);
            acc[2] = fmaf(xj[j], w0.z, acc[2]); acc[3] = fmaf(xj[j], w0.w, acc[3]);
            acc[4] = fmaf(xj[j], w1.x, acc[4]); acc[5] = fmaf(xj[j], w1.y, acc[5]);
            acc[6] = fmaf(xj[j], w1.z, acc[6]); acc[7] = fmaf(xj[j], w1.w, acc[7]);
        }
    }
#pragma unroll
    for (int e = 0; e < 8; ++e) {
        float v = acc[e];
#pragma unroll
        for (int off = 32; off > 0; off >>= 1) v += __shfl_xor(v, off, 64);
        acc[e] = v + bg[e];
    }
    float mx = acc[0];
#pragma unroll
    for (int e = 1; e < 8; ++e) mx = fmaxf(mx, acc[e]);
    float sum = 0.f;
#pragma unroll
    for (int e = 0; e < 8; ++e) { acc[e] = __expf(acc[e] - mx); sum += acc[e]; }
    float inv = 1.0f / sum;
#pragma unroll
    for (int e = 0; e < 8; ++e) acc[e] *= inv;
    if (lane == 0) {
        float4 p0 = {acc[0], acc[1], acc[2], acc[3]};
        float4 p1 = {acc[4], acc[5], acc[6], acc[7]};
        float4* gp = (float4*)(g + (size_t)token * 8);
        gp[0] = p0; gp[1] = p1;
    }
    // x -> f16
    _Float16* xhr = xh + (size_t)token * IN_F;
#pragma unroll
    for (int kc = 0; kc < 4; ++kc) {
        f16x4 h = { (_Float16)xv[kc].x, (_Float16)xv[kc].y,
                    (_Float16)xv[kc].z, (_Float16)xv[kc].w };
        *(f16x4*)(xhr + kc * 256 + lane * 4) = h;
    }
    // out[token][:] = sum_e g_e * be[e][:]
    const float4* be4 = (const float4*)be;
    float4* orow = (float4*)out + (size_t)token * 256;
#pragma unroll
    for (int oc = 0; oc < 4; ++oc) {
        int col4 = oc * 64 + lane;
        float4 a = {0.f, 0.f, 0.f, 0.f};
#pragma unroll
        for (int e = 0; e < 8; ++e) {
            float ge = acc[e];
            float4 b = be4[e * 256 + col4];
            a.x = fmaf(ge, b.x, a.x); a.y = fmaf(ge, b.y, a.y);
            a.z = fmaf(ge, b.z, a.z); a.w = fmaf(ge, b.w, a.w);
        }
        orow[col4] = a;
    }
}

// ---- We [e][i][o] fp32 -> wt2 [o][e*1024+i] f16 (stacked B'^T) ----
__global__ void moe_transpose_we_kernel(const float* __restrict__ We, _Float16* __restrict__ wt) {
    __shared__ float t[64][65];
    int e  = blockIdx.z;
    int i0 = blockIdx.x * 64;   // in_f tile
    int o0 = blockIdx.y * 64;   // out_f tile
    const float* src = We + ((size_t)e << 20);
    int oo = threadIdx.x & 63;
    int ib = threadIdx.x >> 6;  // 0..3
#pragma unroll
    for (int r = 0; r < 16; ++r) {
        int i = ib + r * 4;
        t[i][oo] = src[(size_t)(i0 + i) * OUT_F + o0 + oo];
    }
    __syncthreads();
#pragma unroll
    for (int r = 0; r < 16; ++r) {
        int o = ib + r * 4;
        wt[(size_t)(o0 + o) * KT + (size_t)e * 1024 + i0 + oo] = (_Float16)t[oo][o];
    }
}

// ---- fused GEMM: out += sum_e g[:,e] * (xh @ We[e]); A read from xh, gate in-register ----
__device__ __forceinline__ void async16(const void* gp, void* lp) {
    __builtin_amdgcn_global_load_lds((const __attribute__((address_space(1))) void*)gp,
                                     (__attribute__((address_space(3))) void*)lp, 16, 0, 0);
}

__global__ __launch_bounds__(256, 4) void moe_gemm_kernel(
    const _Float16* __restrict__ xh,   // [M][1024] f16
    const _Float16* __restrict__ wt,   // [N][KT] f16  (stacked B'^T)
    const float* __restrict__ g,       // [M][E]
    float* __restrict__ out)           // [M][N] fp32, atomic accumulate (bias pre-init)
{
    __shared__ __align__(16) _Float16 As[128 * 64];
    __shared__ __align__(16) _Float16 Bs[128 * 64];
    __shared__ float gs[128 * 8];      // [row][e]

    const int tid  = threadIdx.x;
    const int lane = tid & 63;
    const int wave = tid >> 6;
    const size_t m0 = (size_t)blockIdx.y * 128;
    const size_t n0 = (size_t)blockIdx.x * 128;
    const int    z  = blockIdx.z;      // split-K half: experts z*4 .. z*4+3

    ((float4*)gs)[tid] = ((const float4*)(g + m0 * 8))[tid];
    __syncthreads();

    // Staging: linear 16B chunk L = j*256 + tid -> LDS row = L>>3, phys c8 = L&7.
    // XOR swizzle baked into the GLOBAL source: logical k-chunk = phys_c8 ^ (row&7).
    const int rb = tid >> 3;                  // row within 32-row group
    const int c8 = (tid & 7) ^ (rb & 7);      // swizzled logical k-chunk
    const _Float16* pA = xh + (m0 + rb) * (size_t)IN_F + c8 * 8;   // k wraps per expert
    const _Float16* pB = wt + (n0 + rb) * (size_t)KT + (size_t)z * 4096 + c8 * 8;
    char* lA = (char*)As + tid * 16;
    char* lB = (char*)Bs + tid * 16;

    // Fragment read addresses (bytes). A[m=lane&15][k=quad*8+j]; phys c8 = c8_logical ^ (row&7)
    const int quad = lane >> 4;
    const int ml   = lane & 15;
    const int wm   = (wave >> 1) * 64;
    const int wn   = (wave & 1) * 64;
    const int raA0 = (wm + ml) * 128 + (((0 * 4 + quad) ^ (lane & 7)) * 16);
    const int raA1 = (wm + ml) * 128 + (((1 * 4 + quad) ^ (lane & 7)) * 16);
    const int raB0 = (wn + ml) * 128 + (((0 * 4 + quad) ^ (lane & 7)) * 16);
    const int raB1 = (wn + ml) * 128 + (((1 * 4 + quad) ^ (lane & 7)) * 16);

    f32x4 acc[4][4] = {};

    for (int eo = 0; eo < 4; ++eo) {
        const int e = z * 4 + eo;
        // per-lane gate scalars for the 4 m-tiles this lane touches
        _Float16 gh[4];
#pragma unroll
        for (int t = 0; t < 4; ++t) gh[t] = (_Float16)gs[(wm + t * 16 + ml) * 8 + e];
        const _Float16* pBe = pB + eo * 1024;

        for (int kt = 0; kt < 16; ++kt) {
            const _Float16* sA = pA + kt * 64;
            const _Float16* sB = pBe + kt * 64;
#pragma unroll
            for (int j = 0; j < 4; ++j) {
                async16(sA + j * 32 * (size_t)IN_F, lA + j * 4096);
                async16(sB + j * 32 * (size_t)KT,  lB + j * 4096);
            }
            __syncthreads();
#pragma unroll
            for (int s = 0; s < 2; ++s) {
                const int rA = s ? raA1 : raA0;
                const int rB = s ? raB1 : raB0;
                f16x8 af[4], bf[4];
#pragma unroll
                for (int t = 0; t < 4; ++t) af[t] = *(const f16x8*)((const char*)As + rA + t * 2048);
#pragma unroll
                for (int t = 0; t < 4; ++t) bf[t] = *(const f16x8*)((const char*)Bs + rB + t * 2048);
                // gate-scale A fragments: per-lane scalar splat (v_pk_mul_f16)
#pragma unroll
                for (int t = 0; t < 4; ++t) af[t] = af[t] * gh[t];
#pragma unroll
                for (int i = 0; i < 4; ++i)
#pragma unroll
                    for (int jn = 0; jn < 4; ++jn)
                        acc[i][jn] = __builtin_amdgcn_mfma_f32_16x16x32_f16(af[i], bf[jn], acc[i][jn], 0, 0, 0);
            }
            __syncthreads();
        }
    }

    // Epilogue: C/D layout col = lane&15, row = quad*4 + reg. 2-way split-K atomic add.
#pragma unroll
    for (int i = 0; i < 4; ++i) {
        const int rowb = wm + i * 16 + quad * 4;
#pragma unroll
        for (int jn = 0; jn < 4; ++jn) {
            const size_t col = n0 + wn + jn * 16 + ml;
#pragma unroll
            for (int r = 0; r < 4; ++r)
                unsafeAtomicAdd(out + (m0 + rowb + r) * (size_t)OUT_F + col, acc[i][jn][r]);
        }
    }
}

extern "C" void kernel_launch(void* const* d_in, const int* in_sizes, int n_in,
                              void* d_out, int out_size, void* d_ws, size_t ws_size,
                              hipStream_t stream) {
    const float* x  = (const float*)d_in[0];
    const float* We = (const float*)d_in[1];
    const float* be = (const float*)d_in[2];
    const float* Wg = (const float*)d_in[3];
    const float* bg = (const float*)d_in[4];
    float* out = (float*)d_out;

    char* ws = (char*)d_ws;
    float*    g   = (float*)ws;                                  // 256 KB
    _Float16* xh  = (_Float16*)(ws + (1 << 18));                 // 8192*1024*2 = 16 MiB
    _Float16* wt2 = (_Float16*)(ws + (1 << 18) + (1 << 24));     // 1024*8192*2 = 16 MiB
    // total ws needed: ~34 MB

    moe_prep_kernel<<<M_TOK / 4, 256, 0, stream>>>(x, Wg, bg, be, g, xh, out);
    moe_transpose_we_kernel<<<dim3(IN_F / 64, OUT_F / 64, N_EXP), 256, 0, stream>>>(We, wt2);
    moe_gemm_kernel<<<dim3(OUT_F / 128, M_TOK / 128, 2), 256, 0, stream>>>(xh, wt2, g, out);
}